// Round 1
// baseline (111.101 us; speedup 1.0000x reference)
//
#include <hip/hip_runtime.h>
#include <math.h>

#define NB   24
#define FBIN 512
#define ROWS (32*1200)
#define GRID 2048
#define BLK  256

__device__ const int   g_off[NB+1] = {0,3,6,9,12,16,20,24,29,34,40,47,55,64,74,86,100,118,140,169,204,246,304,384,512};
__device__ const float g_k[NB]     = {3,3,3,3,4,4,4,5,5,6,7,8,9,10,12,14,18,22,29,35,42,58,80,128};

__global__ __launch_bounds__(BLK) void pe_main(const float* __restrict__ lm,
                                               const float* __restrict__ re,
                                               const float* __restrict__ im,
                                               const float* __restrict__ S,
                                               float* __restrict__ partial)
{
    __shared__ float s_spec[FBIN];
    __shared__ float s_l10[FBIN];
    __shared__ float s_tq[FBIN];
    __shared__ float s_S[NB*NB];
    __shared__ float s_ct[NB];
    __shared__ float s_ps[192], s_ls[192];
    __shared__ float s_psum[NB], s_toff[NB];
    __shared__ float s_t[NB];
    __shared__ float s_red[BLK];

    const int tid = threadIdx.x;
    const int b0 = 2*tid, b1 = 2*tid+1;

    // bin -> band (row-invariant)
    int seg0 = 0, seg1 = 0;
    for (int b = 0; b < NB; ++b) {
        if (b0 >= g_off[b+1]) seg0++;
        if (b1 >= g_off[b+1]) seg1++;
    }
    const float k0 = g_k[seg0], k1 = g_k[seg1];
    const float w0 = 1.0f/(38400.0f*k0), w1 = 1.0f/(38400.0f*k1);

    // absolute threshold of hearing (row-invariant)
    {
        float z0 = (b0+1)*0.03125f;   // (bin+1)*fs/win/1000 = (bin+1)*31.25/1000
        float z1 = (b1+1)*0.03125f;
        s_tq[b0] = 3.64f*powf(z0+1e-6f,-0.8f) - 6.5f*expf(-0.6f*(z0-3.3f)*(z0-3.3f)) + 1e-3f*z0*z0*z0*z0;
        s_tq[b1] = 3.64f*powf(z1+1e-6f,-0.8f) - 6.5f*expf(-0.6f*(z1-3.3f)*(z1-3.3f)) + 1e-3f*z1*z1*z1*z1;
    }
    for (int i = tid; i < NB*NB; i += BLK) s_S[i] = S[i];
    __syncthreads();
    if (tid < NB) {
        float s = 0.f;
        for (int i = 0; i < NB; ++i) s += s_S[i*NB + tid];
        s_ct[tid] = log10f(s + 1e-8f);
    }
    __syncthreads();

    float acc = 0.f;
    for (int row = blockIdx.x; row < ROWS; row += GRID) {
        const size_t base = (size_t)row * FBIN + b0;
        float2 l2 = *(const float2*)(lm + base);
        float2 r2 = *(const float2*)(re + base);
        float2 i2 = *(const float2*)(im + base);

        float sp0 = expf(fminf(fmaxf(l2.x, -1000.f), 10.f));
        float sp1 = expf(fminf(fmaxf(l2.y, -1000.f), 10.f));
        s_spec[b0] = sp0; s_spec[b1] = sp1;
        s_l10[b0] = log10f(sp0 + 1e-30f);
        s_l10[b1] = log10f(sp1 + 1e-30f);
        __syncthreads();

        // segmented band sums: 8 strided partials per band
        if (tid < 192) {
            int band = tid >> 3, slot = tid & 7;
            int lo = g_off[band], hi = g_off[band+1];
            float ps = 0.f, ls = 0.f;
            for (int j = lo + slot; j < hi; j += 8) { ps += s_spec[j]; ls += s_l10[j]; }
            s_ps[tid] = ps; s_ls[tid] = ls;
        }
        __syncthreads();

        if (tid < NB) {
            float ps = 0.f, ls = 0.f;
            for (int j = 0; j < 8; ++j) { ps += s_ps[tid*8+j]; ls += s_ls[tid*8+j]; }
            s_psum[tid] = ps;
            float k = g_k[tid];
            float geo = exp10f(ls / k);
            float ari = ps / k;
            float sfm = 10.f * log10f(geo/ari + 1e-8f);
            float alpha = fminf(sfm * (-1.f/60.f), 1.f);
            float off = alpha * (14.5f + (float)(tid+1)) + (1.f - alpha) * 5.5f;
            s_toff[tid] = -off * 0.1f;
        }
        __syncthreads();

        if (tid < NB) {
            float c = 0.f;
            for (int i = 0; i < NB; ++i) c += s_psum[i] * s_S[i*NB + tid];
            c = log10f(c + 1e-8f);
            float toff = s_toff[tid];
            s_t[tid] = exp10f(c + toff) / exp10f(s_ct[tid] + toff);
        }
        __syncthreads();

        {
            float t0 = fmaxf(s_t[seg0], s_tq[b0]);
            float t1 = fmaxf(s_t[seg1], s_tq[b1]);
            float sc0 = 2.f / sqrtf(6.f * t0 / k0);
            float sc1 = 2.f / sqrtf(6.f * t1 / k1);
            float pe0 = log2f(fabsf(r2.x*sp0)*sc0 + 1.f) + log2f(fabsf(i2.x*sp0)*sc0 + 1.f);
            float pe1 = log2f(fabsf(r2.y*sp1)*sc1 + 1.f) + log2f(fabsf(i2.y*sp1)*sc1 + 1.f);
            acc += pe0*w0 + pe1*w1;
        }
        __syncthreads();   // protect s_spec/s_l10 before next row overwrite
    }

    s_red[tid] = acc;
    __syncthreads();
    for (int s = BLK/2; s > 0; s >>= 1) {
        if (tid < s) s_red[tid] += s_red[tid+s];
        __syncthreads();
    }
    if (tid == 0) partial[blockIdx.x] = s_red[0];
}

__global__ __launch_bounds__(256) void pe_final(const float* __restrict__ partial,
                                                float* __restrict__ out)
{
    __shared__ double sred[256];
    int tid = threadIdx.x;
    double s = 0.0;
    for (int i = tid; i < GRID; i += 256) s += (double)partial[i];
    sred[tid] = s;
    __syncthreads();
    for (int k = 128; k > 0; k >>= 1) {
        if (tid < k) sred[tid] += sred[tid+k];
        __syncthreads();
    }
    if (tid == 0) out[0] = (float)(1.0 / (sred[0] + 1.0));
}

extern "C" void kernel_launch(void* const* d_in, const int* in_sizes, int n_in,
                              void* d_out, int out_size, void* d_ws, size_t ws_size,
                              hipStream_t stream) {
    const float* lm = (const float*)d_in[0];
    const float* re = (const float*)d_in[1];
    const float* im = (const float*)d_in[2];
    const float* S  = (const float*)d_in[3];
    float* partial = (float*)d_ws;   // GRID floats = 8 KB scratch
    pe_main<<<GRID, BLK, 0, stream>>>(lm, re, im, S, partial);
    pe_final<<<1, 256, 0, stream>>>(partial, (float*)d_out);
}

// Round 2
// 60.203 us; speedup vs baseline: 1.8454x; 1.8454x over previous
//
#include <hip/hip_runtime.h>
#include <math.h>

#define NB    24
#define FBIN  512
#define ROWS  (32*1200)
#define GRID  2048
#define BLK   256
#define WPB   4                 // waves per block
#define NWAVES (GRID*WPB)       // 8192
#define SLOTS 17

__device__ __constant__ int   c_off[NB+1] = {0,3,6,9,12,16,20,24,29,34,40,47,55,64,74,86,100,118,140,169,204,246,304,384,512};
__device__ __constant__ float c_k[NB]     = {3,3,3,3,4,4,4,5,5,6,7,8,9,10,12,14,18,22,29,35,42,58,80,128};

__global__ __launch_bounds__(BLK) void pe_main(const float* __restrict__ lm,
                                               const float* __restrict__ re,
                                               const float* __restrict__ im,
                                               const float* __restrict__ S,
                                               float* __restrict__ partial)
{
    __shared__ float s_S[NB*NB];
    __shared__ float s_invcol[NB];
    __shared__ float s_slot[WPB][NB*SLOTS];
    __shared__ float s_psum[WPB][NB];
    __shared__ float s_t[WPB][NB];

    const int tid  = threadIdx.x;
    const int w    = tid >> 6;
    const int lane = tid & 63;

    // ---- block prologue: S and 1/(colsum+eps), one barrier total ----
    for (int i = tid; i < NB*NB; i += BLK) s_S[i] = S[i];
    __syncthreads();
    if (tid < NB) {
        float cs = 1e-8f;
        for (int i = 0; i < NB; ++i) cs += s_S[i*NB + tid];
        s_invcol[tid] = 1.0f / cs;
    }
    __syncthreads();

    // ---- per-lane row-invariant metadata (8 contiguous bins per lane) ----
    const int bin0 = lane * 8;
    int band[8], waddr[8];
    float tq[8], a4[8];
    #pragma unroll
    for (int j = 0; j < 8; ++j) {
        const int binj = bin0 + j;
        int b = 0;
        for (int q = 0; q < NB; ++q) if (binj >= c_off[q+1]) b++;
        band[j]  = b;
        waddr[j] = b*SLOTS + (lane - (c_off[b] >> 3));
        float z = (binj + 1) * 0.03125f;   // (bin+1)*fs/win/1000
        tq[j] = 3.64f*powf(z + 1e-6f, -0.8f)
              - 6.5f*expf(-0.6f*(z-3.3f)*(z-3.3f))
              + 1e-3f*z*z*z*z;
        a4[j] = 1.5f / c_k[b];             // 2/denom == rsqrt(a4 * t_bin)
    }
    int gn = 0, gbase = 0;
    if (lane < NB) {
        const int clo = c_off[lane] >> 3;
        const int chi = (c_off[lane+1] - 1) >> 3;
        gn = chi - clo + 1;                // <= 16 contributing chunks
        gbase = lane * SLOTS;
    }

    float* const slot  = s_slot[w];
    float* const psum  = s_psum[w];
    float* const tband = s_t[w];
    const int gw = blockIdx.x * WPB + w;

    float acc = 0.f;
    for (int row = gw; row < ROWS; row += NWAVES) {
        const size_t base = (size_t)row * FBIN + bin0;
        const float4 l0 = *(const float4*)(lm + base);
        const float4 l1 = *(const float4*)(lm + base + 4);
        const float4 r0 = *(const float4*)(re + base);
        const float4 r1 = *(const float4*)(re + base + 4);
        const float4 i0 = *(const float4*)(im + base);
        const float4 i1 = *(const float4*)(im + base + 4);

        const float lmv[8] = {l0.x,l0.y,l0.z,l0.w,l1.x,l1.y,l1.z,l1.w};
        float sp[8];
        #pragma unroll
        for (int j = 0; j < 8; ++j)
            sp[j] = __builtin_amdgcn_exp2f(fminf(fmaxf(lmv[j], -1000.f), 10.f) * 1.44269504f);

        // segmented per-band partial sums -> per-wave LDS slots
        {
            float ps = sp[0]; int wa = waddr[0];
            #pragma unroll
            for (int j = 1; j < 8; ++j) {
                if (waddr[j] == wa) ps += sp[j];
                else { slot[wa] = ps; wa = waddr[j]; ps = sp[j]; }
            }
            slot[wa] = ps;
        }
        asm volatile("s_waitcnt lgkmcnt(0)" ::: "memory");

        if (lane < NB) {
            float p = 0.f;
            for (int m = 0; m < gn; ++m) p += slot[gbase + m];
            psum[lane] = p;
            asm volatile("s_waitcnt lgkmcnt(0)" ::: "memory");
            float c = 1e-8f;
            for (int i = 0; i < NB; ++i) c = fmaf(psum[i], s_S[i*NB + lane], c);
            tband[lane] = c * s_invcol[lane];   // t = (psum@S+eps)/(colsum+eps); toff cancels
        }
        asm volatile("s_waitcnt lgkmcnt(0)" ::: "memory");

        const float rv[8] = {r0.x,r0.y,r0.z,r0.w,r1.x,r1.y,r1.z,r1.w};
        const float iv[8] = {i0.x,i0.y,i0.z,i0.w,i1.x,i1.y,i1.z,i1.w};
        #pragma unroll
        for (int j = 0; j < 8; ++j) {
            const float t = fmaxf(tband[band[j]], tq[j]);
            const float s = __builtin_amdgcn_rsqf(a4[j] * t);
            const float u = sp[j] * s;
            const float per = __builtin_amdgcn_logf(fmaf(fabsf(rv[j]), u, 1.0f));
            const float pei = __builtin_amdgcn_logf(fmaf(fabsf(iv[j]), u, 1.0f));
            acc = fmaf(per + pei, a4[j], acc);   // w == a4 / 57600
        }
        asm volatile("s_waitcnt lgkmcnt(0)" ::: "memory");  // slot reuse guard
    }

    // wave reduction, one partial per wave (deterministic)
    #pragma unroll
    for (int o = 32; o > 0; o >>= 1) acc += __shfl_xor(acc, o, 64);
    if (lane == 0) partial[gw] = acc * (1.0f/57600.0f);
}

__global__ __launch_bounds__(256) void pe_final(const float* __restrict__ partial,
                                                float* __restrict__ out)
{
    __shared__ double sred[256];
    const int tid = threadIdx.x;
    double s = 0.0;
    for (int i = tid; i < NWAVES; i += 256) s += (double)partial[i];
    sred[tid] = s;
    __syncthreads();
    for (int k = 128; k > 0; k >>= 1) {
        if (tid < k) sred[tid] += sred[tid+k];
        __syncthreads();
    }
    if (tid == 0) out[0] = (float)(1.0 / (sred[0] + 1.0));
}

extern "C" void kernel_launch(void* const* d_in, const int* in_sizes, int n_in,
                              void* d_out, int out_size, void* d_ws, size_t ws_size,
                              hipStream_t stream) {
    const float* lm = (const float*)d_in[0];
    const float* re = (const float*)d_in[1];
    const float* im = (const float*)d_in[2];
    const float* S  = (const float*)d_in[3];
    float* partial = (float*)d_ws;   // NWAVES floats = 32 KB scratch
    pe_main<<<GRID, BLK, 0, stream>>>(lm, re, im, S, partial);
    pe_final<<<1, 256, 0, stream>>>(partial, (float*)d_out);
}